// Round 9
// baseline (462.908 us; speedup 1.0000x reference)
//
#include <hip/hip_runtime.h>

#define N_NODES 100000
#define N_EDGES 1600000
#define N_GRAPHS 512
#define MPAD 100096      // 782 * 128 (also 1564 * 64)
#define NBUCK 782        // buckets of 128 nodes (dst >> 7)
#define BCAP 3072        // per-bucket ebin capacity; mean 2046, sigma ~45 -> 22 sigma margin
#define BCOL 3968        // per-bucket col window: BCAP + 7*128 pad worst case
#define NGROUPS 6250     // 100000 / 16 row-groups for fused gemm
#define GEMM_BLOCKS 256  // 1 block/CU; 512 regressed twice (R5 spill, R6 fixed-overhead doubling)
#define AGG_BLOCKS 2048  // 8 blocks/CU -> 32 waves/CU full occupancy; grid-stride ~12 nodes/wave
#define AGG_NW (AGG_BLOCKS * 4)
#define NSLOT 8          // pooling slot window per block
#define WSTR 144         // LDS row stride (elems) for weight stage + h buffers

typedef unsigned short ushortT;
typedef unsigned char u8;
typedef __attribute__((ext_vector_type(8))) short bf16x8;
typedef __attribute__((ext_vector_type(4))) float f32x4;
typedef __attribute__((ext_vector_type(2))) float f32x2;
typedef __attribute__((ext_vector_type(4))) unsigned int uint4v;

__device__ inline float bf2f(ushortT u) {
    unsigned int x = ((unsigned int)u) << 16;
    return __builtin_bit_cast(float, x);
}
__device__ inline ushortT f2bf(float f) {
    unsigned int x = __builtin_bit_cast(unsigned int, f);
    unsigned int r = (x + 0x7fffu + ((x >> 16) & 1u)) >> 16;
    return (ushortT)r;
}

// ---------------- fp8 e4m3 conversion (HW cvt on gfx950; manual fallback) ----------------
#if defined(__has_builtin)
#if __has_builtin(__builtin_amdgcn_cvt_pk_f32_fp8) && __has_builtin(__builtin_amdgcn_cvt_pk_fp8_f32)
#define HW_FP8 1
#endif
#endif

__device__ inline f32x2 fp8x2_f32(unsigned short u) {
#ifdef HW_FP8
    return __builtin_amdgcn_cvt_pk_f32_fp8((int)(unsigned int)u, false);
#else
    f32x2 r;
#pragma unroll
    for (int i = 0; i < 2; ++i) {
        unsigned int b = (u >> (8 * i)) & 0xFFu;
        unsigned int s = (b >> 7) << 31;
        unsigned int em = b & 0x7Fu;
        float v;
        if (em == 0) v = 0.f;
        else if ((em >> 3) == 0) v = (float)(em & 7) * 0.001953125f;   // subnormal m/8 * 2^-6
        else {
            unsigned int f32b = ((((em >> 3) - 7 + 127)) << 23) | ((em & 7) << 20);
            v = __builtin_bit_cast(float, f32b);
        }
        r[i] = __builtin_bit_cast(float, __builtin_bit_cast(unsigned int, v) | s);
    }
    return r;
#endif
}

#ifndef HW_FP8
__device__ inline u8 f2fp8_sw(float f) {
    unsigned int b = __builtin_bit_cast(unsigned int, f);
    u8 s = (u8)((b >> 24) & 0x80);
    float a = __builtin_bit_cast(float, b & 0x7FFFFFFF);
    if (a >= 448.f) return s | 0x7E;
    if (a < 0.0078125f) return s;            // flush < 2^-7
    unsigned int ab = __builtin_bit_cast(unsigned int, a);
    ab += 0x0007FFFF + ((ab >> 20) & 1);     // RTNE at bit 20
    int e = (int)((ab >> 23) & 0xFF) - 120;
    if (e >= 16) return s | 0x7E;
    if (e <= 0) return s;
    return s | (u8)((e << 3) | ((ab >> 20) & 7));
}
#endif

__device__ inline unsigned int f32x2_fp8(float a, float b) {     // 2 bytes in low 16
#ifdef HW_FP8
    return (unsigned int)__builtin_amdgcn_cvt_pk_fp8_f32(a, b, 0, false) & 0xFFFFu;
#else
    return (unsigned int)f2fp8_sw(a) | ((unsigned int)f2fp8_sw(b) << 8);
#endif
}
__device__ inline u8 f2fp8(float y) {
#ifdef HW_FP8
    return (u8)(__builtin_amdgcn_cvt_pk_fp8_f32(y, y, 0, false) & 0xFF);
#else
    return f2fp8_sw(y);
#endif
}

// ======== PROLOGUE: weight-prep | pbuf zero | C pad-row zero | gcur zero | x->fp8 cvt ========
__global__ __launch_bounds__(256) void k_pre_rest(
    const float* __restrict__ x,
    const float* __restrict__ w11, const float* __restrict__ w12,
    const float* __restrict__ w21, const float* __restrict__ w22,
    const float* __restrict__ w31, const float* __restrict__ w32,
    const float* __restrict__ b11, const float* __restrict__ g1, const float* __restrict__ be1, const float* __restrict__ b12,
    const float* __restrict__ b21, const float* __restrict__ g2, const float* __restrict__ be2, const float* __restrict__ b22,
    const float* __restrict__ b31, const float* __restrict__ g3, const float* __restrict__ be3, const float* __restrict__ b32,
    int* __restrict__ gcur,
    ushortT* __restrict__ Wt, float* __restrict__ addv,
    u8* __restrict__ Xf8, u8* __restrict__ C0, u8* __restrict__ C1, float* __restrict__ pbuf)
{
    int bid = blockIdx.x, t = threadIdx.x;
    if (bid < 386) {
        const float rs = rsqrtf(1.0f + 1e-5f);
        if (bid < 384) {
            int idx = bid * 256 + t;
            int m = idx >> 14;
            int r = idx & 16383;
            int k = r & 127;
            int n = r >> 7;
            const float* W = (m == 0) ? w11 : (m == 1) ? w12 : (m == 2) ? w21
                           : (m == 3) ? w22 : (m == 4) ? w31 : w32;
            float v = W[k * 128 + n];
            if ((m & 1) == 0) {
                const float* gm = (m == 0) ? g1 : (m == 2) ? g2 : g3;
                v *= gm[n] * rs;
            }
            Wt[m * 16384 + n * 128 + k] = f2bf(v);
        } else if (bid == 384) {
            if (t < 384) {
                int L = t >> 7, n = t & 127;
                const float* bb = (L == 0) ? b11 : (L == 1) ? b21 : b31;
                const float* gm = (L == 0) ? g1 : (L == 1) ? g2 : g3;
                const float* be = (L == 0) ? be1 : (L == 1) ? be2 : be3;
                float s = gm[n] * rs;
                addv[(2 * L) * 128 + n] = bb[n] * s + be[n];
            }
        } else {
            if (t < 384) {
                int L = t >> 7, n = t & 127;
                const float* bb = (L == 0) ? b12 : (L == 1) ? b22 : b32;
                addv[(2 * L + 1) * 128 + n] = bb[n];
            }
        }
    } else if (bid < 434) {
        int i4 = (bid - 386) * 256 + t;
        *(float4*)&pbuf[i4 * 4] = make_float4(0.f, 0.f, 0.f, 0.f);
    } else if (bid == 434) {
        // zero pad row (index N_NODES) of C0 and C1: 128 B each
        if (t < 32) *(unsigned int*)&C0[(size_t)N_NODES * 128 + t * 4] = 0u;
        else if (t < 64) *(unsigned int*)&C1[(size_t)N_NODES * 128 + (t - 32) * 4] = 0u;
    } else if (bid == 435) {
        for (int i = t; i < NBUCK; i += 256) gcur[i] = 0;
    } else {
        // x (fp32) -> fp8, zero pad rows
        size_t i = ((size_t)(bid - 436) * 256 + t) * 4;   // element index
        unsigned int o = 0u;
        if (i < (size_t)N_NODES * 128) {
            float4 v = *(const float4*)&x[i];
            o = f32x2_fp8(v.x, v.y) | (f32x2_fp8(v.z, v.w) << 16);
        }
        *(unsigned int*)&Xf8[i] = o;
    }
}

// ======== edge scatter into dst-range buckets; 1024 threads/block ========
__global__ __launch_bounds__(1024) void k_scatter(const int* __restrict__ src, const int* __restrict__ dst,
                                                  int* __restrict__ gcur, int2* __restrict__ ebin) {
    __shared__ int lcnt[NBUCK];
    __shared__ int lbase[NBUCK];
    int t = threadIdx.x;
    int e0 = blockIdx.x * (N_EDGES / 256);
    int e1 = e0 + (N_EDGES / 256);
    for (int i = t; i < NBUCK; i += 1024) lcnt[i] = 0;
    __syncthreads();
    for (int e = e0 + t; e < e1; e += 1024) atomicAdd(&lcnt[dst[e] >> 7], 1);
    __syncthreads();
    for (int i = t; i < NBUCK; i += 1024) {
        int c = lcnt[i];
        lbase[i] = c ? atomicAdd(&gcur[i], c) : 0;
    }
    __syncthreads();
    for (int i = t; i < NBUCK; i += 1024) lcnt[i] = 0;
    __syncthreads();
    for (int e = e0 + t; e < e1; e += 1024) {
        int d = dst[e];
        int b = d >> 7;
        int off = atomicAdd(&lcnt[b], 1);
        ebin[(size_t)b * BCAP + lbase[b] + off] = make_int2(src[e], d);
    }
}

// ======== per-bucket CSR build: histogram + LDS scan + place + pad ========
// col[] stores BYTE offsets (src << 7) so k_agg skips the shift in its gather chain.
__global__ __launch_bounds__(256) void kb_build(const int2* __restrict__ ebin, const int* __restrict__ gcur,
                                                int* __restrict__ col, int* __restrict__ pstart,
                                                int* __restrict__ pend) {
    __shared__ int cnt[128];
    __shared__ int pc[128];
    __shared__ int ps[128];
    __shared__ int cur[128];
    int b = blockIdx.x, t = threadIdx.x;
    if (t < 128) cnt[t] = 0;
    __syncthreads();
    int m = gcur[b];
    const int2* eb = ebin + (size_t)b * BCAP;
    for (int e = t; e < m; e += 256) atomicAdd(&cnt[eb[e].y & 127], 1);
    __syncthreads();
    if (t < 128) pc[t] = (cnt[t] + 7) & ~7;
    __syncthreads();
    for (int off = 1; off < 128; off <<= 1) {
        int v = (t < 128 && t >= off) ? pc[t - off] : 0;
        __syncthreads();
        if (t < 128) pc[t] += v;
        __syncthreads();
    }
    if (t < 128) {
        int padded = (cnt[t] + 7) & ~7;
        int start = b * BCOL + pc[t] - padded;
        ps[t] = start;
        cur[t] = 0;
        int node = b * 128 + t;
        if (node < N_NODES) {
            pstart[node] = start;
            pend[node] = start + padded;
        }
    }
    __syncthreads();
    for (int e = t; e < m; e += 256) {
        int2 sd = eb[e];
        int idx = sd.y & 127;
        int pos = ps[idx] + atomicAdd(&cur[idx], 1);
        col[pos] = sd.x << 7;
    }
    __syncthreads();
    if (t < 128) {
        int s = ps[t] + cnt[t];
        int e = ps[t] + ((cnt[t] + 7) & ~7);
        for (int j = s; j < e; ++j) col[j] = N_NODES << 7;
    }
}

// ---- gather helpers: accumulate 16 (or 8) neighbor feature-pairs given col byte-offsets ----
__device__ inline void gather16(const u8* __restrict__ Xb, int4 c0, int4 c1, int4 c2, int4 c3, f32x2& acc) {
    unsigned short u0 = *(const unsigned short*)(Xb + (unsigned int)c0.x);
    unsigned short u1 = *(const unsigned short*)(Xb + (unsigned int)c0.y);
    unsigned short u2 = *(const unsigned short*)(Xb + (unsigned int)c0.z);
    unsigned short u3 = *(const unsigned short*)(Xb + (unsigned int)c0.w);
    unsigned short u4 = *(const unsigned short*)(Xb + (unsigned int)c1.x);
    unsigned short u5 = *(const unsigned short*)(Xb + (unsigned int)c1.y);
    unsigned short u6 = *(const unsigned short*)(Xb + (unsigned int)c1.z);
    unsigned short u7 = *(const unsigned short*)(Xb + (unsigned int)c1.w);
    unsigned short u8_ = *(const unsigned short*)(Xb + (unsigned int)c2.x);
    unsigned short u9 = *(const unsigned short*)(Xb + (unsigned int)c2.y);
    unsigned short u10 = *(const unsigned short*)(Xb + (unsigned int)c2.z);
    unsigned short u11 = *(const unsigned short*)(Xb + (unsigned int)c2.w);
    unsigned short u12 = *(const unsigned short*)(Xb + (unsigned int)c3.x);
    unsigned short u13 = *(const unsigned short*)(Xb + (unsigned int)c3.y);
    unsigned short u14 = *(const unsigned short*)(Xb + (unsigned int)c3.z);
    unsigned short u15 = *(const unsigned short*)(Xb + (unsigned int)c3.w);
    f32x2 t0 = fp8x2_f32(u0) + fp8x2_f32(u1);
    f32x2 t1 = fp8x2_f32(u2) + fp8x2_f32(u3);
    f32x2 t2 = fp8x2_f32(u4) + fp8x2_f32(u5);
    f32x2 t3 = fp8x2_f32(u6) + fp8x2_f32(u7);
    f32x2 t4 = fp8x2_f32(u8_) + fp8x2_f32(u9);
    f32x2 t5 = fp8x2_f32(u10) + fp8x2_f32(u11);
    f32x2 t6 = fp8x2_f32(u12) + fp8x2_f32(u13);
    f32x2 t7 = fp8x2_f32(u14) + fp8x2_f32(u15);
    acc += ((t0 + t1) + (t2 + t3)) + ((t4 + t5) + (t6 + t7));
}
__device__ inline void gather8(const u8* __restrict__ Xb, int4 c0, int4 c1, f32x2& acc) {
    unsigned short u0 = *(const unsigned short*)(Xb + (unsigned int)c0.x);
    unsigned short u1 = *(const unsigned short*)(Xb + (unsigned int)c0.y);
    unsigned short u2 = *(const unsigned short*)(Xb + (unsigned int)c0.z);
    unsigned short u3 = *(const unsigned short*)(Xb + (unsigned int)c0.w);
    unsigned short u4 = *(const unsigned short*)(Xb + (unsigned int)c1.x);
    unsigned short u5 = *(const unsigned short*)(Xb + (unsigned int)c1.y);
    unsigned short u6 = *(const unsigned short*)(Xb + (unsigned int)c1.z);
    unsigned short u7 = *(const unsigned short*)(Xb + (unsigned int)c1.w);
    f32x2 t0 = fp8x2_f32(u0) + fp8x2_f32(u1);
    f32x2 t1 = fp8x2_f32(u2) + fp8x2_f32(u3);
    f32x2 t2 = fp8x2_f32(u4) + fp8x2_f32(u5);
    f32x2 t3 = fp8x2_f32(u6) + fp8x2_f32(u7);
    acc += (t0 + t1) + (t2 + t3);
}

// ------- aggregation: T[i](bf16) = X[i] + sum_j X[col[j]], X in fp8 -------
// DEPTH-2 SOFTWARE PIPELINE over a grid-stride node loop: each iteration issues
// meta(n+2) and the 16-col prefetch for n+1 (whose meta arrived last iteration),
// then processes node n whose cols were prefetched a FULL iteration ago.
// Per-node exposed latency drops from 3 dependent memory rounds to ~1 (the gathers).
// 2048 blocks -> 32 waves/CU (full occupancy), ~12 nodes/wave.  [R8: -9 us/dispatch]
__global__ __launch_bounds__(256) void k_agg(const u8* __restrict__ X, const int* __restrict__ pstart,
                                             const int* __restrict__ pend, const int* __restrict__ col,
                                             ushortT* __restrict__ T) {
    const int lane = threadIdx.x & 63;
    const int wid = blockIdx.x * 4 + (threadIdx.x >> 6);
    const u8* Xb = X + lane * 2;

    int n0 = wid;
    int n1 = wid + AGG_NW;
    int lo0 = 0, hi0 = 0, lo1 = 0, hi1 = 0;
    unsigned short s0 = 0, s1 = 0;
    int4 A0 = {0,0,0,0}, B0 = {0,0,0,0}, Cv0 = {0,0,0,0}, D0 = {0,0,0,0};

    // prologue: meta+cols for n0, meta for n1
    if (n0 < N_NODES) {
        lo0 = pstart[n0]; hi0 = pend[n0];
        s0 = *(const unsigned short*)(Xb + ((size_t)n0 << 7));
        if (lo0 < hi0) {
            A0 = *(const int4*)&col[lo0];
            B0 = *(const int4*)&col[lo0 + 4];
            Cv0 = *(const int4*)&col[lo0 + 8];   // colA has +256B slack for over-read
            D0 = *(const int4*)&col[lo0 + 12];
        }
    }
    if (n1 < N_NODES) {
        lo1 = pstart[n1]; hi1 = pend[n1];
        s1 = *(const unsigned short*)(Xb + ((size_t)n1 << 7));
    }

    while (n0 < MPAD) {
        // stage A: issue meta prefetch for n2
        int n2 = n1 + AGG_NW;
        int lo2 = 0, hi2 = 0;
        unsigned short s2 = 0;
        if (n2 < N_NODES) {
            lo2 = pstart[n2]; hi2 = pend[n2];
            s2 = *(const unsigned short*)(Xb + ((size_t)n2 << 7));
        }
        // stage B: issue col prefetch for n1 (lo1 fetched last iteration -> no stall)
        int4 A1 = {0,0,0,0}, B1 = {0,0,0,0}, Cv1 = {0,0,0,0}, D1 = {0,0,0,0};
        if (n1 < MPAD && lo1 < hi1) {
            A1 = *(const int4*)&col[lo1];
            B1 = *(const int4*)&col[lo1 + 4];
            Cv1 = *(const int4*)&col[lo1 + 8];
            D1 = *(const int4*)&col[lo1 + 12];
        }
        // stage C: process n0 (cols prefetched a full iteration ago)
        if (n0 >= N_NODES) {
            *(unsigned int*)&T[(size_t)n0 * 128 + lane * 2] = 0u;
        } else {
            f32x2 acc = fp8x2_f32(s0);
            int j = lo0;
            int rem = hi0 - lo0;
            if (rem >= 16) {
                gather16(Xb, A0, B0, Cv0, D0, acc);
                j += 16;
            } else if (rem >= 8) {
                gather8(Xb, A0, B0, acc);
                j += 8;
            }
            while (j + 16 <= hi0) {
                int4 c0 = *(const int4*)&col[j];
                int4 c1 = *(const int4*)&col[j + 4];
                int4 c2 = *(const int4*)&col[j + 8];
                int4 c3 = *(const int4*)&col[j + 12];
                gather16(Xb, c0, c1, c2, c3, acc);
                j += 16;
            }
            if (j < hi0) {   // exactly one 8-batch (padded deg % 8 == 0)
                int4 c0 = *(const int4*)&col[j];
                int4 c1 = *(const int4*)&col[j + 4];
                gather8(Xb, c0, c1, acc);
            }
            unsigned int o = ((unsigned int)f2bf(acc.y) << 16) | (unsigned int)f2bf(acc.x);
            *(unsigned int*)&T[(size_t)n0 * 128 + lane * 2] = o;
        }
        // rotate pipeline state
        n0 = n1; lo0 = lo1; hi0 = hi1; s0 = s1;
        A0 = A1; B0 = B1; Cv0 = Cv1; D0 = D1;
        n1 = n2; lo1 = lo2; hi1 = hi2; s1 = s2;
    }
}

// ======== FUSED DOUBLE-GEMM + POOL (persistent, register-resident weights) ========
// 256 blocks x 256 threads, 1 wave/SIMD (R5/R6: occupancy levers regressed; keep 1 w/SIMD).
// R7 epilogue (best measured): fire-and-forget ds_add per lane, NO register psum across
// iterations (R8: psum+curg coupling broke the LOADA prefetch overlap, 42->59 us), NO shfl
// chains (R6: 2-deep dependent cross-lane exposes ~200cy/chunk at 1 wave/SIMD). All batch
// ids prefetched (double-buffered) alongside the A-fragments.
__global__ __launch_bounds__(256, 1) void k_gemm_f(const ushortT* __restrict__ A,
                                                   const ushortT* __restrict__ W1, const float* __restrict__ add1,
                                                   const ushortT* __restrict__ W2, const float* __restrict__ add2,
                                                   u8* __restrict__ C, const int* __restrict__ batch,
                                                   float* __restrict__ P, int off) {
    __shared__ ushortT wl[128 * WSTR];   // 36864 B: weight stage, then per-wave h buffers
    __shared__ float pws[NSLOT * 128];   // 4096 B pooling slots
    const int tid = threadIdx.x;
    const int wave = tid >> 6, lane = tid & 63;
    const int l16 = lane & 15, quad = lane >> 4;

    // contiguous group range for this block
    const int bb = blockIdx.x;
    const int gq = NGROUPS / GEMM_BLOCKS, grm = NGROUPS % GEMM_BLOCKS;
    const int gs = bb * gq + (bb < grm ? bb : grm);
    const int ge = gs + gq + (bb < grm ? 1 : 0);
    const int g0blk = batch[gs * 16];

    for (int i = tid; i < NSLOT * 128; i += 256) pws[i] = 0.f;

    // ---- one-time: stage W1/W2 through LDS, pull fragments into registers ----
    bf16x8 w1f[32], w2f[32];
#pragma unroll
    for (int it = 0; it < 8; ++it) {
        int idx = (it * 256 + tid) * 8;
        *(uint4v*)&wl[(idx >> 7) * WSTR + (idx & 127)] = *(const uint4v*)&W1[idx];
    }
    __syncthreads();
#pragma unroll
    for (int c = 0; c < 8; ++c)
#pragma unroll
        for (int kc = 0; kc < 4; ++kc)
            w1f[c * 4 + kc] = *(const bf16x8*)&wl[(c * 16 + l16) * WSTR + kc * 32 + quad * 8];
    __syncthreads();
#pragma unroll
    for (int it = 0; it < 8; ++it) {
        int idx = (it * 256 + tid) * 8;
        *(uint4v*)&wl[(idx >> 7) * WSTR + (idx & 127)] = *(const uint4v*)&W2[idx];
    }
    __syncthreads();
#pragma unroll
    for (int c = 0; c < 8; ++c)
#pragma unroll
        for (int kc = 0; kc < 4; ++kc)
            w2f[c * 4 + kc] = *(const bf16x8*)&wl[(c * 16 + l16) * WSTR + kc * 32 + quad * 8];
    __syncthreads();

    // hoisted biases: GEMM1 cols are c*16+quad*4+r (float4); GEMM2 cols are c*16+l16
    f32x4 add1v[8];
    float add2s[8];
#pragma unroll
    for (int c = 0; c < 8; ++c) {
        add1v[c] = *(const f32x4*)&add1[c * 16 + quad * 4];
        add2s[c] = add2[c * 16 + l16];
    }

    ushortT* hb = wl + wave * (16 * WSTR);   // per-wave private h buffer

    auto LOADA = [&](bf16x8 (&af)[4], int2& bp, int4& br, int g) {
        const ushortT* ap = A + (size_t)(g * 16 + l16) * 128 + quad * 8;
#pragma unroll
        for (int kc = 0; kc < 4; ++kc) af[kc] = *(const bf16x8*)(ap + kc * 32);
        bp.x = batch[g * 16];
        bp.y = batch[g * 16 + 15];
        br = *(const int4*)&batch[g * 16 + quad * 4];   // this lane's 4 row graph ids
    };

    auto BODY = [&](bf16x8 (&af)[4], const int2& bp, const int4& br, int g) {
        const int base = g * 16;
        f32x4 acc[8];
#pragma unroll
        for (int c = 0; c < 8; ++c) acc[c] = (f32x4){0.f, 0.f, 0.f, 0.f};
        // GEMM1 swapped: acc[c] = h^T chunk; lane -> row l16, cols c*16+quad*4+reg
#pragma unroll
        for (int kc = 0; kc < 4; ++kc)
#pragma unroll
            for (int c = 0; c < 8; ++c)
                acc[c] = __builtin_amdgcn_mfma_f32_16x16x32_bf16(w1f[c * 4 + kc], af[kc], acc[c], 0, 0, 0);
        // h = relu(acc + b1'), pack 4 bf16 -> one b64 LDS write per chunk
#pragma unroll
        for (int c = 0; c < 8; ++c) {
            float y0 = acc[c][0] + add1v[c][0]; y0 = y0 > 0.f ? y0 : 0.f;
            float y1 = acc[c][1] + add1v[c][1]; y1 = y1 > 0.f ? y1 : 0.f;
            float y2 = acc[c][2] + add1v[c][2]; y2 = y2 > 0.f ? y2 : 0.f;
            float y3 = acc[c][3] + add1v[c][3]; y3 = y3 > 0.f ? y3 : 0.f;
            uint2 pk;
            pk.x = (unsigned int)f2bf(y0) | ((unsigned int)f2bf(y1) << 16);
            pk.y = (unsigned int)f2bf(y2) | ((unsigned int)f2bf(y3) << 16);
            *(uint2*)&hb[l16 * WSTR + c * 16 + quad * 4] = pk;
        }
        // read h rows back as GEMM2 A-fragments (within-wave exchange, no barrier)
        bf16x8 af2[4];
#pragma unroll
        for (int kc = 0; kc < 4; ++kc)
            af2[kc] = *(const bf16x8*)&hb[l16 * WSTR + kc * 32 + quad * 8];
        // GEMM2 normal: lane -> rows base+quad*4+r, col c*16+l16
#pragma unroll
        for (int c = 0; c < 8; ++c) acc[c] = (f32x4){0.f, 0.f, 0.f, 0.f};
#pragma unroll
        for (int kc = 0; kc < 4; ++kc)
#pragma unroll
            for (int c = 0; c < 8; ++c)
                acc[c] = __builtin_amdgcn_mfma_f32_16x16x32_bf16(af2[kc], w2f[c * 4 + kc], acc[c], 0, 0, 0);

        const int b0 = bp.x;
        const bool fast = (bp.x == bp.y);
#pragma unroll
        for (int c = 0; c < 8; ++c) {
            int n = c * 16 + l16;
            float ad = add2s[c];
            float y0 = acc[c][0] + ad; y0 = y0 > 0.f ? y0 : 0.f;
            float y1 = acc[c][1] + ad; y1 = y1 > 0.f ? y1 : 0.f;
            float y2 = acc[c][2] + ad; y2 = y2 > 0.f ? y2 : 0.f;
            float y3 = acc[c][3] + ad; y3 = y3 > 0.f ? y3 : 0.f;
            if (C) {
                size_t rbase = (size_t)(base + quad * 4) * 128 + n;
                C[rbase] = f2fp8(y0);
                C[rbase + 128] = f2fp8(y1);
                C[rbase + 256] = f2fp8(y2);
                C[rbase + 384] = f2fp8(y3);
            }
            if (fast) {
                // fire-and-forget ds_add of this lane's 4-row partial
                float s = (y0 + y1) + (y2 + y3);
                int slot = b0 - g0blk;
                if (slot < NSLOT) atomicAdd(&pws[slot * 128 + n], s);
                else atomicAdd(&P[b0 * 384 + off + n], s);
            } else {
                int slot0 = br.x - g0blk;
                if (slot0 < NSLOT) atomicAdd(&pws[slot0 * 128 + n], y0);
                else atomicAdd(&P[br.x * 384 + off + n], y0);
                int slot1 = br.y - g0blk;
                if (slot1 < NSLOT) atomicAdd(&pws[slot1 * 128 + n], y1);
                else atomicAdd(&P[br.y * 384 + off + n], y1);
                int slot2 = br.z - g0blk;
                if (slot2 < NSLOT) atomicAdd(&pws[slot2 * 128 + n], y2);
                else atomicAdd(&P[br.z * 384 + off + n], y2);
                int slot3 = br.w - g0blk;
                if (slot3 < NSLOT) atomicAdd(&pws[slot3 * 128 + n], y3);
                else atomicAdd(&P[br.w * 384 + off + n], y3);
            }
        }
    };

    // steady-state loop: groups gs+wave, gs+wave+4, ... with double-buffered A+batch prefetch
    int g = gs + wave;
    if (g < ge) {
        bf16x8 afA[4], afB[4];
        int2 bpA, bpB;
        int4 brA, brB;
        LOADA(afA, bpA, brA, g);
        while (true) {
            int gn = g + 4;
            if (gn < ge) LOADA(afB, bpB, brB, gn);
            BODY(afA, bpA, brA, g);
            g = gn;
            if (g >= ge) break;
            gn = g + 4;
            if (gn < ge) LOADA(afA, bpA, brA, gn);
            BODY(afB, bpB, brB, g);
            g = gn;
            if (g >= ge) break;
        }
    }

    __syncthreads();
    for (int i = tid; i < NSLOT * 128; i += 256) {
        float v = pws[i];
        if (v != 0.f) atomicAdd(&P[(g0blk + (i >> 7)) * 384 + off + (i & 127)], v);
    }
}

// ---------------- head: out = relu(P @ W1 + b1) @ W2 + b2  (all fp32) ------------
__global__ __launch_bounds__(384) void k_head(const float* __restrict__ P, const float* __restrict__ W1,
                                              const float* __restrict__ B1, const float* __restrict__ W2,
                                              const float* __restrict__ B2, float* __restrict__ out) {
    __shared__ float pr[384];
    __shared__ float qr[384];
    int g = blockIdx.x, t = threadIdx.x;
    pr[t] = P[g * 384 + t];
    __syncthreads();
    float a = 0.f;
    for (int k = 0; k < 384; ++k) a += pr[k] * W1[k * 384 + t];
    a += B1[t];
    qr[t] = a > 0.f ? a : 0.f;
    __syncthreads();
    if (t < 10) {
        float o = 0.f;
        for (int k = 0; k < 384; ++k) o += qr[k] * W2[k * 10 + t];
        o += B2[t];
        out[g * 10 + t] = o;
    }
}

extern "C" void kernel_launch(void* const* d_in, const int* in_sizes, int n_in,
                              void* d_out, int out_size, void* d_ws, size_t ws_size,
                              hipStream_t stream) {
    const float* x     = (const float*)d_in[0];
    const int*   ei    = (const int*)d_in[1];
    const int*   srcA  = ei;
    const int*   dstA  = ei + N_EDGES;
    const int*   batch = (const int*)d_in[2];
    const float* c1_w1 = (const float*)d_in[3];
    const float* c1_b1 = (const float*)d_in[4];
    const float* c1_g  = (const float*)d_in[5];
    const float* c1_be = (const float*)d_in[6];
    const float* c1_w2 = (const float*)d_in[7];
    const float* c1_b2 = (const float*)d_in[8];
    const float* c2_w1 = (const float*)d_in[9];
    const float* c2_b1 = (const float*)d_in[10];
    const float* c2_g  = (const float*)d_in[11];
    const float* c2_be = (const float*)d_in[12];
    const float* c2_w2 = (const float*)d_in[13];
    const float* c2_b2 = (const float*)d_in[14];
    const float* c3_w1 = (const float*)d_in[15];
    const float* c3_b1 = (const float*)d_in[16];
    const float* c3_g  = (const float*)d_in[17];
    const float* c3_be = (const float*)d_in[18];
    const float* c3_w2 = (const float*)d_in[19];
    const float* c3_b2 = (const float*)d_in[20];
    const float* l1w   = (const float*)d_in[21];
    const float* l1b   = (const float*)d_in[22];
    const float* l2w   = (const float*)d_in[23];
    const float* l2b   = (const float*)d_in[24];
    float* out = (float*)d_out;

    size_t o = 0;
    char* base = (char*)d_ws;
    auto alloc = [&](size_t n) -> char* {
        char* p = base + o;
        o += (n + 255) & ~(size_t)255;
        return p;
    };
    ushortT* Wt    = (ushortT*)alloc(6 * 16384 * 2);
    float*   addv  = (float*)alloc(6 * 128 * 4);
    int*     gcur  = (int*)alloc((size_t)NBUCK * 4);
    int*     pst   = (int*)alloc((size_t)N_NODES * 4);
    int*     pen   = (int*)alloc((size_t)N_NODES * 4);
    int*     colA  = (int*)alloc((size_t)NBUCK * BCOL * 4 + 256);  // +slack for 16-col over-read
    ushortT* T     = (ushortT*)alloc((size_t)MPAD * 128 * 2);   // agg out (bf16); ebin aliases
    u8*      Xf8   = (u8*)alloc((size_t)MPAD * 128);            // x in fp8
    u8*      C0    = (u8*)alloc((size_t)MPAD * 128);            // L0 out fp8
    u8*      C1    = (u8*)alloc((size_t)MPAD * 128);            // L1 out fp8
    float*   pbuf  = (float*)alloc((size_t)N_GRAPHS * 384 * 4);
    int2*    ebin  = (int2*)T;   // 19.2 MB <= 25.6 MB; dead before first k_agg

    k_pre_rest<<<436 + 12512, 256, 0, stream>>>(x,
                                                c1_w1, c1_w2, c2_w1, c2_w2, c3_w1, c3_w2,
                                                c1_b1, c1_g, c1_be, c1_b2,
                                                c2_b1, c2_g, c2_be, c2_b2,
                                                c3_b1, c3_g, c3_be, c3_b2,
                                                gcur, Wt, addv, Xf8, C0, C1, pbuf);
    k_scatter<<<256, 1024, 0, stream>>>(srcA, dstA, gcur, ebin);
    kb_build<<<NBUCK, 256, 0, stream>>>(ebin, gcur, colA, pst, pen);

    // L0: Xf8 -> (agg) T -> (gemm+pool) C0 ; L1: C0 -> T -> C1 ; L2: C1 -> T -> (pool only)
    k_agg<<<AGG_BLOCKS, 256, 0, stream>>>(Xf8, pst, pen, colA, T);
    k_gemm_f<<<GEMM_BLOCKS, 256, 0, stream>>>(T, Wt + 0 * 16384, addv + 0 * 128,
                                              Wt + 1 * 16384, addv + 1 * 128, C0, batch, pbuf, 0);
    k_agg<<<AGG_BLOCKS, 256, 0, stream>>>(C0, pst, pen, colA, T);
    k_gemm_f<<<GEMM_BLOCKS, 256, 0, stream>>>(T, Wt + 2 * 16384, addv + 2 * 128,
                                              Wt + 3 * 16384, addv + 3 * 128, C1, batch, pbuf, 128);
    k_agg<<<AGG_BLOCKS, 256, 0, stream>>>(C1, pst, pen, colA, T);
    k_gemm_f<<<GEMM_BLOCKS, 256, 0, stream>>>(T, Wt + 4 * 16384, addv + 4 * 128,
                                              Wt + 5 * 16384, addv + 5 * 128, (u8*)nullptr, batch, pbuf, 256);

    k_head<<<N_GRAPHS, 384, 0, stream>>>(pbuf, l1w, l1b, l2w, l2b, out);
}

// Round 10
// 414.517 us; speedup vs baseline: 1.1167x; 1.1167x over previous
//
#include <hip/hip_runtime.h>

#define N_NODES 100000
#define N_EDGES 1600000
#define N_GRAPHS 512
#define MPAD 100096      // 782 * 128 (also 1564 * 64)
#define NBUCK 782        // buckets of 128 nodes (dst >> 7)
#define BCAP 3072        // per-bucket ebin capacity; mean 2046, sigma ~45 -> 22 sigma margin
#define BCOL 3968        // per-bucket col window: BCAP + 7*128 pad worst case
#define NGROUPS 6250     // 100000 / 16 row-groups for fused gemm
#define GEMM_BLOCKS 256  // 1 block/CU; 512 regressed twice (R5 spill, R6 fixed-overhead doubling)
#define NSLOT 8          // pooling slot window per block
#define WSTR 144         // LDS row stride (elems) for weight stage + h buffers

typedef unsigned short ushortT;
typedef unsigned char u8;
typedef __attribute__((ext_vector_type(8))) short bf16x8;
typedef __attribute__((ext_vector_type(4))) float f32x4;
typedef __attribute__((ext_vector_type(2))) float f32x2;
typedef __attribute__((ext_vector_type(4))) unsigned int uint4v;

__device__ inline float bf2f(ushortT u) {
    unsigned int x = ((unsigned int)u) << 16;
    return __builtin_bit_cast(float, x);
}
__device__ inline ushortT f2bf(float f) {
    unsigned int x = __builtin_bit_cast(unsigned int, f);
    unsigned int r = (x + 0x7fffu + ((x >> 16) & 1u)) >> 16;
    return (ushortT)r;
}

// ---------------- fp8 e4m3 conversion (HW cvt on gfx950; manual fallback) ----------------
#if defined(__has_builtin)
#if __has_builtin(__builtin_amdgcn_cvt_pk_f32_fp8) && __has_builtin(__builtin_amdgcn_cvt_pk_fp8_f32)
#define HW_FP8 1
#endif
#endif

__device__ inline f32x2 fp8x2_f32(unsigned short u) {
#ifdef HW_FP8
    return __builtin_amdgcn_cvt_pk_f32_fp8((int)(unsigned int)u, false);
#else
    f32x2 r;
#pragma unroll
    for (int i = 0; i < 2; ++i) {
        unsigned int b = (u >> (8 * i)) & 0xFFu;
        unsigned int s = (b >> 7) << 31;
        unsigned int em = b & 0x7Fu;
        float v;
        if (em == 0) v = 0.f;
        else if ((em >> 3) == 0) v = (float)(em & 7) * 0.001953125f;   // subnormal m/8 * 2^-6
        else {
            unsigned int f32b = ((((em >> 3) - 7 + 127)) << 23) | ((em & 7) << 20);
            v = __builtin_bit_cast(float, f32b);
        }
        r[i] = __builtin_bit_cast(float, __builtin_bit_cast(unsigned int, v) | s);
    }
    return r;
#endif
}

#ifndef HW_FP8
__device__ inline u8 f2fp8_sw(float f) {
    unsigned int b = __builtin_bit_cast(unsigned int, f);
    u8 s = (u8)((b >> 24) & 0x80);
    float a = __builtin_bit_cast(float, b & 0x7FFFFFFF);
    if (a >= 448.f) return s | 0x7E;
    if (a < 0.0078125f) return s;            // flush < 2^-7
    unsigned int ab = __builtin_bit_cast(unsigned int, a);
    ab += 0x0007FFFF + ((ab >> 20) & 1);     // RTNE at bit 20
    int e = (int)((ab >> 23) & 0xFF) - 120;
    if (e >= 16) return s | 0x7E;
    if (e <= 0) return s;
    return s | (u8)((e << 3) | ((ab >> 20) & 7));
}
#endif

__device__ inline unsigned int f32x2_fp8(float a, float b) {     // 2 bytes in low 16
#ifdef HW_FP8
    return (unsigned int)__builtin_amdgcn_cvt_pk_fp8_f32(a, b, 0, false) & 0xFFFFu;
#else
    return (unsigned int)f2fp8_sw(a) | ((unsigned int)f2fp8_sw(b) << 8);
#endif
}
__device__ inline u8 f2fp8(float y) {
#ifdef HW_FP8
    return (u8)(__builtin_amdgcn_cvt_pk_fp8_f32(y, y, 0, false) & 0xFF);
#else
    return f2fp8_sw(y);
#endif
}

// ======== PROLOGUE: weight-prep | pbuf zero | C pad-row zero | gcur zero | x->fp8 cvt ========
__global__ __launch_bounds__(256) void k_pre_rest(
    const float* __restrict__ x,
    const float* __restrict__ w11, const float* __restrict__ w12,
    const float* __restrict__ w21, const float* __restrict__ w22,
    const float* __restrict__ w31, const float* __restrict__ w32,
    const float* __restrict__ b11, const float* __restrict__ g1, const float* __restrict__ be1, const float* __restrict__ b12,
    const float* __restrict__ b21, const float* __restrict__ g2, const float* __restrict__ be2, const float* __restrict__ b22,
    const float* __restrict__ b31, const float* __restrict__ g3, const float* __restrict__ be3, const float* __restrict__ b32,
    int* __restrict__ gcur,
    ushortT* __restrict__ Wt, float* __restrict__ addv,
    u8* __restrict__ Xf8, u8* __restrict__ C0, u8* __restrict__ C1, float* __restrict__ pbuf)
{
    int bid = blockIdx.x, t = threadIdx.x;
    if (bid < 386) {
        const float rs = rsqrtf(1.0f + 1e-5f);
        if (bid < 384) {
            int idx = bid * 256 + t;
            int m = idx >> 14;
            int r = idx & 16383;
            int k = r & 127;
            int n = r >> 7;
            const float* W = (m == 0) ? w11 : (m == 1) ? w12 : (m == 2) ? w21
                           : (m == 3) ? w22 : (m == 4) ? w31 : w32;
            float v = W[k * 128 + n];
            if ((m & 1) == 0) {
                const float* gm = (m == 0) ? g1 : (m == 2) ? g2 : g3;
                v *= gm[n] * rs;
            }
            Wt[m * 16384 + n * 128 + k] = f2bf(v);
        } else if (bid == 384) {
            if (t < 384) {
                int L = t >> 7, n = t & 127;
                const float* bb = (L == 0) ? b11 : (L == 1) ? b21 : b31;
                const float* gm = (L == 0) ? g1 : (L == 1) ? g2 : g3;
                const float* be = (L == 0) ? be1 : (L == 1) ? be2 : be3;
                float s = gm[n] * rs;
                addv[(2 * L) * 128 + n] = bb[n] * s + be[n];
            }
        } else {
            if (t < 384) {
                int L = t >> 7, n = t & 127;
                const float* bb = (L == 0) ? b12 : (L == 1) ? b22 : b32;
                addv[(2 * L + 1) * 128 + n] = bb[n];
            }
        }
    } else if (bid < 434) {
        int i4 = (bid - 386) * 256 + t;
        *(float4*)&pbuf[i4 * 4] = make_float4(0.f, 0.f, 0.f, 0.f);
    } else if (bid == 434) {
        // zero pad row (index N_NODES) of C0 and C1: 128 B each
        if (t < 32) *(unsigned int*)&C0[(size_t)N_NODES * 128 + t * 4] = 0u;
        else if (t < 64) *(unsigned int*)&C1[(size_t)N_NODES * 128 + (t - 32) * 4] = 0u;
    } else if (bid == 435) {
        for (int i = t; i < NBUCK; i += 256) gcur[i] = 0;
    } else {
        // x (fp32) -> fp8, zero pad rows
        size_t i = ((size_t)(bid - 436) * 256 + t) * 4;   // element index
        unsigned int o = 0u;
        if (i < (size_t)N_NODES * 128) {
            float4 v = *(const float4*)&x[i];
            o = f32x2_fp8(v.x, v.y) | (f32x2_fp8(v.z, v.w) << 16);
        }
        *(unsigned int*)&Xf8[i] = o;
    }
}

// ======== edge scatter into dst-range buckets; 1024 threads/block ========
__global__ __launch_bounds__(1024) void k_scatter(const int* __restrict__ src, const int* __restrict__ dst,
                                                  int* __restrict__ gcur, int2* __restrict__ ebin) {
    __shared__ int lcnt[NBUCK];
    __shared__ int lbase[NBUCK];
    int t = threadIdx.x;
    int e0 = blockIdx.x * (N_EDGES / 256);
    int e1 = e0 + (N_EDGES / 256);
    for (int i = t; i < NBUCK; i += 1024) lcnt[i] = 0;
    __syncthreads();
    for (int e = e0 + t; e < e1; e += 1024) atomicAdd(&lcnt[dst[e] >> 7], 1);
    __syncthreads();
    for (int i = t; i < NBUCK; i += 1024) {
        int c = lcnt[i];
        lbase[i] = c ? atomicAdd(&gcur[i], c) : 0;
    }
    __syncthreads();
    for (int i = t; i < NBUCK; i += 1024) lcnt[i] = 0;
    __syncthreads();
    for (int e = e0 + t; e < e1; e += 1024) {
        int d = dst[e];
        int b = d >> 7;
        int off = atomicAdd(&lcnt[b], 1);
        ebin[(size_t)b * BCAP + lbase[b] + off] = make_int2(src[e], d);
    }
}

// ======== per-bucket CSR build: histogram + LDS scan + place + pad ========
// col[] stores BYTE offsets (src << 7) so k_agg skips the shift in its gather chain.
__global__ __launch_bounds__(256) void kb_build(const int2* __restrict__ ebin, const int* __restrict__ gcur,
                                                int* __restrict__ col, int* __restrict__ pstart,
                                                int* __restrict__ pend) {
    __shared__ int cnt[128];
    __shared__ int pc[128];
    __shared__ int ps[128];
    __shared__ int cur[128];
    int b = blockIdx.x, t = threadIdx.x;
    if (t < 128) cnt[t] = 0;
    __syncthreads();
    int m = gcur[b];
    const int2* eb = ebin + (size_t)b * BCAP;
    for (int e = t; e < m; e += 256) atomicAdd(&cnt[eb[e].y & 127], 1);
    __syncthreads();
    if (t < 128) pc[t] = (cnt[t] + 7) & ~7;
    __syncthreads();
    for (int off = 1; off < 128; off <<= 1) {
        int v = (t < 128 && t >= off) ? pc[t - off] : 0;
        __syncthreads();
        if (t < 128) pc[t] += v;
        __syncthreads();
    }
    if (t < 128) {
        int padded = (cnt[t] + 7) & ~7;
        int start = b * BCOL + pc[t] - padded;
        ps[t] = start;
        cur[t] = 0;
        int node = b * 128 + t;
        if (node < N_NODES) {
            pstart[node] = start;
            pend[node] = start + padded;
        }
    }
    __syncthreads();
    for (int e = t; e < m; e += 256) {
        int2 sd = eb[e];
        int idx = sd.y & 127;
        int pos = ps[idx] + atomicAdd(&cur[idx], 1);
        col[pos] = sd.x << 7;
    }
    __syncthreads();
    if (t < 128) {
        int s = ps[t] + cnt[t];
        int e = ps[t] + ((cnt[t] + 7) & ~7);
        for (int j = s; j < e; ++j) col[j] = N_NODES << 7;
    }
}

// ------- aggregation: T[i](bf16) = X[i] + sum_j X[col[j]], X in fp8 -------
// Gather-THROUGHPUT-bound (R9 falsified chain-latency theory: depth-2 pipeline cost
// +14 us/dispatch). Best measured structure: one wave per node (dynamic churn), lane =
// feature pair, 16 INDEPENDENT gathers in flight per iteration.
__global__ __launch_bounds__(256) void k_agg(const u8* __restrict__ X, const int* __restrict__ pstart,
                                             const int* __restrict__ pend, const int* __restrict__ col,
                                             ushortT* __restrict__ T) {
    int gid = blockIdx.x * 4 + (threadIdx.x >> 6);
    int lane = threadIdx.x & 63;
    if (gid >= MPAD) return;
    if (gid >= N_NODES) {
        *(unsigned int*)&T[(size_t)gid * 128 + lane * 2] = 0u;
        return;
    }
    const u8* Xb = X + lane * 2;
    int lo = pstart[gid], hi = pend[gid];
    unsigned short v = *(const unsigned short*)(Xb + ((size_t)gid << 7));
    f32x2 acc = fp8x2_f32(v);
    int j = lo;
    while (j + 16 <= hi) {
        int4 c0 = *(const int4*)&col[j];
        int4 c1 = *(const int4*)&col[j + 4];
        int4 c2 = *(const int4*)&col[j + 8];
        int4 c3 = *(const int4*)&col[j + 12];
        unsigned short u0 = *(const unsigned short*)(Xb + (unsigned int)c0.x);
        unsigned short u1 = *(const unsigned short*)(Xb + (unsigned int)c0.y);
        unsigned short u2 = *(const unsigned short*)(Xb + (unsigned int)c0.z);
        unsigned short u3 = *(const unsigned short*)(Xb + (unsigned int)c0.w);
        unsigned short u4 = *(const unsigned short*)(Xb + (unsigned int)c1.x);
        unsigned short u5 = *(const unsigned short*)(Xb + (unsigned int)c1.y);
        unsigned short u6 = *(const unsigned short*)(Xb + (unsigned int)c1.z);
        unsigned short u7 = *(const unsigned short*)(Xb + (unsigned int)c1.w);
        unsigned short u8_ = *(const unsigned short*)(Xb + (unsigned int)c2.x);
        unsigned short u9 = *(const unsigned short*)(Xb + (unsigned int)c2.y);
        unsigned short u10 = *(const unsigned short*)(Xb + (unsigned int)c2.z);
        unsigned short u11 = *(const unsigned short*)(Xb + (unsigned int)c2.w);
        unsigned short u12 = *(const unsigned short*)(Xb + (unsigned int)c3.x);
        unsigned short u13 = *(const unsigned short*)(Xb + (unsigned int)c3.y);
        unsigned short u14 = *(const unsigned short*)(Xb + (unsigned int)c3.z);
        unsigned short u15 = *(const unsigned short*)(Xb + (unsigned int)c3.w);
        f32x2 t0 = fp8x2_f32(u0) + fp8x2_f32(u1);
        f32x2 t1 = fp8x2_f32(u2) + fp8x2_f32(u3);
        f32x2 t2 = fp8x2_f32(u4) + fp8x2_f32(u5);
        f32x2 t3 = fp8x2_f32(u6) + fp8x2_f32(u7);
        f32x2 t4 = fp8x2_f32(u8_) + fp8x2_f32(u9);
        f32x2 t5 = fp8x2_f32(u10) + fp8x2_f32(u11);
        f32x2 t6 = fp8x2_f32(u12) + fp8x2_f32(u13);
        f32x2 t7 = fp8x2_f32(u14) + fp8x2_f32(u15);
        acc += ((t0 + t1) + (t2 + t3)) + ((t4 + t5) + (t6 + t7));
        j += 16;
    }
    if (j < hi) {   // exactly one 8-batch (padded deg % 8 == 0)
        int4 c0 = *(const int4*)&col[j];
        int4 c1 = *(const int4*)&col[j + 4];
        unsigned short u0 = *(const unsigned short*)(Xb + (unsigned int)c0.x);
        unsigned short u1 = *(const unsigned short*)(Xb + (unsigned int)c0.y);
        unsigned short u2 = *(const unsigned short*)(Xb + (unsigned int)c0.z);
        unsigned short u3 = *(const unsigned short*)(Xb + (unsigned int)c0.w);
        unsigned short u4 = *(const unsigned short*)(Xb + (unsigned int)c1.x);
        unsigned short u5 = *(const unsigned short*)(Xb + (unsigned int)c1.y);
        unsigned short u6 = *(const unsigned short*)(Xb + (unsigned int)c1.z);
        unsigned short u7 = *(const unsigned short*)(Xb + (unsigned int)c1.w);
        f32x2 t0 = fp8x2_f32(u0) + fp8x2_f32(u1);
        f32x2 t1 = fp8x2_f32(u2) + fp8x2_f32(u3);
        f32x2 t2 = fp8x2_f32(u4) + fp8x2_f32(u5);
        f32x2 t3 = fp8x2_f32(u6) + fp8x2_f32(u7);
        acc += (t0 + t1) + (t2 + t3);
    }
    unsigned int o = ((unsigned int)f2bf(acc.y) << 16) | (unsigned int)f2bf(acc.x);
    *(unsigned int*)&T[(size_t)gid * 128 + lane * 2] = o;
}

// ======== FUSED DOUBLE-GEMM + POOL (persistent, register-resident weights) ========
// 256 blocks x 256 threads, 1 wave/SIMD (R5/R6: occupancy levers regressed; keep 1 w/SIMD).
// Best-measured epilogue (R7, 417.6 us total): fire-and-forget ds_add per lane, NO register
// psum across iterations (R8: psum+curg coupling broke LOADA prefetch overlap, 42->59 us),
// NO shfl chains (R6: dependent cross-lane exposes ~200cy/chunk at 1 wave/SIMD). All batch
// ids prefetched (double-buffered) alongside the A-fragments.
__global__ __launch_bounds__(256, 1) void k_gemm_f(const ushortT* __restrict__ A,
                                                   const ushortT* __restrict__ W1, const float* __restrict__ add1,
                                                   const ushortT* __restrict__ W2, const float* __restrict__ add2,
                                                   u8* __restrict__ C, const int* __restrict__ batch,
                                                   float* __restrict__ P, int off) {
    __shared__ ushortT wl[128 * WSTR];   // 36864 B: weight stage, then per-wave h buffers
    __shared__ float pws[NSLOT * 128];   // 4096 B pooling slots
    const int tid = threadIdx.x;
    const int wave = tid >> 6, lane = tid & 63;
    const int l16 = lane & 15, quad = lane >> 4;

    // contiguous group range for this block
    const int bb = blockIdx.x;
    const int gq = NGROUPS / GEMM_BLOCKS, grm = NGROUPS % GEMM_BLOCKS;
    const int gs = bb * gq + (bb < grm ? bb : grm);
    const int ge = gs + gq + (bb < grm ? 1 : 0);
    const int g0blk = batch[gs * 16];

    for (int i = tid; i < NSLOT * 128; i += 256) pws[i] = 0.f;

    // ---- one-time: stage W1/W2 through LDS, pull fragments into registers ----
    bf16x8 w1f[32], w2f[32];
#pragma unroll
    for (int it = 0; it < 8; ++it) {
        int idx = (it * 256 + tid) * 8;
        *(uint4v*)&wl[(idx >> 7) * WSTR + (idx & 127)] = *(const uint4v*)&W1[idx];
    }
    __syncthreads();
#pragma unroll
    for (int c = 0; c < 8; ++c)
#pragma unroll
        for (int kc = 0; kc < 4; ++kc)
            w1f[c * 4 + kc] = *(const bf16x8*)&wl[(c * 16 + l16) * WSTR + kc * 32 + quad * 8];
    __syncthreads();
#pragma unroll
    for (int it = 0; it < 8; ++it) {
        int idx = (it * 256 + tid) * 8;
        *(uint4v*)&wl[(idx >> 7) * WSTR + (idx & 127)] = *(const uint4v*)&W2[idx];
    }
    __syncthreads();
#pragma unroll
    for (int c = 0; c < 8; ++c)
#pragma unroll
        for (int kc = 0; kc < 4; ++kc)
            w2f[c * 4 + kc] = *(const bf16x8*)&wl[(c * 16 + l16) * WSTR + kc * 32 + quad * 8];
    __syncthreads();

    // hoisted biases: GEMM1 cols are c*16+quad*4+r (float4); GEMM2 cols are c*16+l16
    f32x4 add1v[8];
    float add2s[8];
#pragma unroll
    for (int c = 0; c < 8; ++c) {
        add1v[c] = *(const f32x4*)&add1[c * 16 + quad * 4];
        add2s[c] = add2[c * 16 + l16];
    }

    ushortT* hb = wl + wave * (16 * WSTR);   // per-wave private h buffer

    auto LOADA = [&](bf16x8 (&af)[4], int2& bp, int4& br, int g) {
        const ushortT* ap = A + (size_t)(g * 16 + l16) * 128 + quad * 8;
#pragma unroll
        for (int kc = 0; kc < 4; ++kc) af[kc] = *(const bf16x8*)(ap + kc * 32);
        bp.x = batch[g * 16];
        bp.y = batch[g * 16 + 15];
        br = *(const int4*)&batch[g * 16 + quad * 4];   // this lane's 4 row graph ids
    };

    auto BODY = [&](bf16x8 (&af)[4], const int2& bp, const int4& br, int g) {
        const int base = g * 16;
        f32x4 acc[8];
#pragma unroll
        for (int c = 0; c < 8; ++c) acc[c] = (f32x4){0.f, 0.f, 0.f, 0.f};
        // GEMM1 swapped: acc[c] = h^T chunk; lane -> row l16, cols c*16+quad*4+reg
#pragma unroll
        for (int kc = 0; kc < 4; ++kc)
#pragma unroll
            for (int c = 0; c < 8; ++c)
                acc[c] = __builtin_amdgcn_mfma_f32_16x16x32_bf16(w1f[c * 4 + kc], af[kc], acc[c], 0, 0, 0);
        // h = relu(acc + b1'), pack 4 bf16 -> one b64 LDS write per chunk
#pragma unroll
        for (int c = 0; c < 8; ++c) {
            float y0 = acc[c][0] + add1v[c][0]; y0 = y0 > 0.f ? y0 : 0.f;
            float y1 = acc[c][1] + add1v[c][1]; y1 = y1 > 0.f ? y1 : 0.f;
            float y2 = acc[c][2] + add1v[c][2]; y2 = y2 > 0.f ? y2 : 0.f;
            float y3 = acc[c][3] + add1v[c][3]; y3 = y3 > 0.f ? y3 : 0.f;
            uint2 pk;
            pk.x = (unsigned int)f2bf(y0) | ((unsigned int)f2bf(y1) << 16);
            pk.y = (unsigned int)f2bf(y2) | ((unsigned int)f2bf(y3) << 16);
            *(uint2*)&hb[l16 * WSTR + c * 16 + quad * 4] = pk;
        }
        // read h rows back as GEMM2 A-fragments (within-wave exchange, no barrier)
        bf16x8 af2[4];
#pragma unroll
        for (int kc = 0; kc < 4; ++kc)
            af2[kc] = *(const bf16x8*)&hb[l16 * WSTR + kc * 32 + quad * 8];
        // GEMM2 normal: lane -> rows base+quad*4+r, col c*16+l16
#pragma unroll
        for (int c = 0; c < 8; ++c) acc[c] = (f32x4){0.f, 0.f, 0.f, 0.f};
#pragma unroll
        for (int kc = 0; kc < 4; ++kc)
#pragma unroll
            for (int c = 0; c < 8; ++c)
                acc[c] = __builtin_amdgcn_mfma_f32_16x16x32_bf16(af2[kc], w2f[c * 4 + kc], acc[c], 0, 0, 0);

        const int b0 = bp.x;
        const bool fast = (bp.x == bp.y);
#pragma unroll
        for (int c = 0; c < 8; ++c) {
            int n = c * 16 + l16;
            float ad = add2s[c];
            float y0 = acc[c][0] + ad; y0 = y0 > 0.f ? y0 : 0.f;
            float y1 = acc[c][1] + ad; y1 = y1 > 0.f ? y1 : 0.f;
            float y2 = acc[c][2] + ad; y2 = y2 > 0.f ? y2 : 0.f;
            float y3 = acc[c][3] + ad; y3 = y3 > 0.f ? y3 : 0.f;
            if (C) {
                size_t rbase = (size_t)(base + quad * 4) * 128 + n;
                C[rbase] = f2fp8(y0);
                C[rbase + 128] = f2fp8(y1);
                C[rbase + 256] = f2fp8(y2);
                C[rbase + 384] = f2fp8(y3);
            }
            if (fast) {
                // fire-and-forget ds_add of this lane's 4-row partial
                float s = (y0 + y1) + (y2 + y3);
                int slot = b0 - g0blk;
                if (slot < NSLOT) atomicAdd(&pws[slot * 128 + n], s);
                else atomicAdd(&P[b0 * 384 + off + n], s);
            } else {
                int slot0 = br.x - g0blk;
                if (slot0 < NSLOT) atomicAdd(&pws[slot0 * 128 + n], y0);
                else atomicAdd(&P[br.x * 384 + off + n], y0);
                int slot1 = br.y - g0blk;
                if (slot1 < NSLOT) atomicAdd(&pws[slot1 * 128 + n], y1);
                else atomicAdd(&P[br.y * 384 + off + n], y1);
                int slot2 = br.z - g0blk;
                if (slot2 < NSLOT) atomicAdd(&pws[slot2 * 128 + n], y2);
                else atomicAdd(&P[br.z * 384 + off + n], y2);
                int slot3 = br.w - g0blk;
                if (slot3 < NSLOT) atomicAdd(&pws[slot3 * 128 + n], y3);
                else atomicAdd(&P[br.w * 384 + off + n], y3);
            }
        }
    };

    // steady-state loop: groups gs+wave, gs+wave+4, ... with double-buffered A+batch prefetch
    int g = gs + wave;
    if (g < ge) {
        bf16x8 afA[4], afB[4];
        int2 bpA, bpB;
        int4 brA, brB;
        LOADA(afA, bpA, brA, g);
        while (true) {
            int gn = g + 4;
            if (gn < ge) LOADA(afB, bpB, brB, gn);
            BODY(afA, bpA, brA, g);
            g = gn;
            if (g >= ge) break;
            gn = g + 4;
            if (gn < ge) LOADA(afA, bpA, brA, gn);
            BODY(afB, bpB, brB, g);
            g = gn;
            if (g >= ge) break;
        }
    }

    __syncthreads();
    for (int i = tid; i < NSLOT * 128; i += 256) {
        float v = pws[i];
        if (v != 0.f) atomicAdd(&P[(g0blk + (i >> 7)) * 384 + off + (i & 127)], v);
    }
}

// ---------------- head: out = relu(P @ W1 + b1) @ W2 + b2  (all fp32) ------------
__global__ __launch_bounds__(384) void k_head(const float* __restrict__ P, const float* __restrict__ W1,
                                              const float* __restrict__ B1, const float* __restrict__ W2,
                                              const float* __restrict__ B2, float* __restrict__ out) {
    __shared__ float pr[384];
    __shared__ float qr[384];
    int g = blockIdx.x, t = threadIdx.x;
    pr[t] = P[g * 384 + t];
    __syncthreads();
    float a = 0.f;
    for (int k = 0; k < 384; ++k) a += pr[k] * W1[k * 384 + t];
    a += B1[t];
    qr[t] = a > 0.f ? a : 0.f;
    __syncthreads();
    if (t < 10) {
        float o = 0.f;
        for (int k = 0; k < 384; ++k) o += qr[k] * W2[k * 10 + t];
        o += B2[t];
        out[g * 10 + t] = o;
    }
}

extern "C" void kernel_launch(void* const* d_in, const int* in_sizes, int n_in,
                              void* d_out, int out_size, void* d_ws, size_t ws_size,
                              hipStream_t stream) {
    const float* x     = (const float*)d_in[0];
    const int*   ei    = (const int*)d_in[1];
    const int*   srcA  = ei;
    const int*   dstA  = ei + N_EDGES;
    const int*   batch = (const int*)d_in[2];
    const float* c1_w1 = (const float*)d_in[3];
    const float* c1_b1 = (const float*)d_in[4];
    const float* c1_g  = (const float*)d_in[5];
    const float* c1_be = (const float*)d_in[6];
    const float* c1_w2 = (const float*)d_in[7];
    const float* c1_b2 = (const float*)d_in[8];
    const float* c2_w1 = (const float*)d_in[9];
    const float* c2_b1 = (const float*)d_in[10];
    const float* c2_g  = (const float*)d_in[11];
    const float* c2_be = (const float*)d_in[12];
    const float* c2_w2 = (const float*)d_in[13];
    const float* c2_b2 = (const float*)d_in[14];
    const float* c3_w1 = (const float*)d_in[15];
    const float* c3_b1 = (const float*)d_in[16];
    const float* c3_g  = (const float*)d_in[17];
    const float* c3_be = (const float*)d_in[18];
    const float* c3_w2 = (const float*)d_in[19];
    const float* c3_b2 = (const float*)d_in[20];
    const float* l1w   = (const float*)d_in[21];
    const float* l1b   = (const float*)d_in[22];
    const float* l2w   = (const float*)d_in[23];
    const float* l2b   = (const float*)d_in[24];
    float* out = (float*)d_out;

    size_t o = 0;
    char* base = (char*)d_ws;
    auto alloc = [&](size_t n) -> char* {
        char* p = base + o;
        o += (n + 255) & ~(size_t)255;
        return p;
    };
    ushortT* Wt    = (ushortT*)alloc(6 * 16384 * 2);
    float*   addv  = (float*)alloc(6 * 128 * 4);
    int*     gcur  = (int*)alloc((size_t)NBUCK * 4);
    int*     pst   = (int*)alloc((size_t)N_NODES * 4);
    int*     pen   = (int*)alloc((size_t)N_NODES * 4);
    int*     colA  = (int*)alloc((size_t)NBUCK * BCOL * 4);
    ushortT* T     = (ushortT*)alloc((size_t)MPAD * 128 * 2);   // agg out (bf16); ebin aliases
    u8*      Xf8   = (u8*)alloc((size_t)MPAD * 128);            // x in fp8
    u8*      C0    = (u8*)alloc((size_t)MPAD * 128);            // L0 out fp8
    u8*      C1    = (u8*)alloc((size_t)MPAD * 128);            // L1 out fp8
    float*   pbuf  = (float*)alloc((size_t)N_GRAPHS * 384 * 4);
    int2*    ebin  = (int2*)T;   // 19.2 MB <= 25.6 MB; dead before first k_agg

    k_pre_rest<<<436 + 12512, 256, 0, stream>>>(x,
                                                c1_w1, c1_w2, c2_w1, c2_w2, c3_w1, c3_w2,
                                                c1_b1, c1_g, c1_be, c1_b2,
                                                c2_b1, c2_g, c2_be, c2_b2,
                                                c3_b1, c3_g, c3_be, c3_b2,
                                                gcur, Wt, addv, Xf8, C0, C1, pbuf);
    k_scatter<<<256, 1024, 0, stream>>>(srcA, dstA, gcur, ebin);
    kb_build<<<NBUCK, 256, 0, stream>>>(ebin, gcur, colA, pst, pen);

    // L0: Xf8 -> (agg) T -> (gemm+pool) C0 ; L1: C0 -> T -> C1 ; L2: C1 -> T -> (pool only)
    k_agg<<<MPAD / 4, 256, 0, stream>>>(Xf8, pst, pen, colA, T);
    k_gemm_f<<<GEMM_BLOCKS, 256, 0, stream>>>(T, Wt + 0 * 16384, addv + 0 * 128,
                                              Wt + 1 * 16384, addv + 1 * 128, C0, batch, pbuf, 0);
    k_agg<<<MPAD / 4, 256, 0, stream>>>(C0, pst, pen, colA, T);
    k_gemm_f<<<GEMM_BLOCKS, 256, 0, stream>>>(T, Wt + 2 * 16384, addv + 2 * 128,
                                              Wt + 3 * 16384, addv + 3 * 128, C1, batch, pbuf, 128);
    k_agg<<<MPAD / 4, 256, 0, stream>>>(C1, pst, pen, colA, T);
    k_gemm_f<<<GEMM_BLOCKS, 256, 0, stream>>>(T, Wt + 4 * 16384, addv + 4 * 128,
                                              Wt + 5 * 16384, addv + 5 * 128, (u8*)nullptr, batch, pbuf, 256);

    k_head<<<N_GRAPHS, 384, 0, stream>>>(pbuf, l1w, l1b, l2w, l2b, out);
}